// Round 5
// baseline (198.548 us; speedup 1.0000x reference)
//
#include <hip/hip_runtime.h>
#include <math.h>

#define DIN    2048
#define DOUT   128
#define BHALF  4096
#define NTOT   8192
#define NSPLIT 16
#define JSPAN  512    // NTOT / NSPLIT

typedef __bf16 bf16x8 __attribute__((ext_vector_type(8)));
typedef float  f32x4  __attribute__((ext_vector_type(4)));
typedef unsigned int u32x4 __attribute__((ext_vector_type(4)));

#define MFMA16 __builtin_amdgcn_mfma_f32_16x16x32_bf16

struct PackedPair { unsigned int h, l; };

__device__ __forceinline__ unsigned int bf16_rne(float f) {
    unsigned int u = __float_as_uint(f);
    return (u + 0x7fffu + ((u >> 16) & 1u)) >> 16;
}
__device__ __forceinline__ float bf16f(unsigned int h) {
    return __uint_as_float(h << 16);
}
__device__ __forceinline__ PackedPair split2(float a, float b) {
    unsigned int h0 = bf16_rne(a), h1 = bf16_rne(b);
    unsigned int g0 = bf16_rne(a - bf16f(h0)), g1 = bf16_rne(b - bf16f(h1));
    PackedPair r;
    r.h = h0 | (h1 << 16);
    r.l = g0 | (g1 << 16);
    return r;
}

// Packed fragment layout for a matrix row r, feature k (K-tiles of 32):
//   group g = r>>4, ks = k>>5, lane = (r&15) | (((k>>3)&3)<<4), elem e = k&7
//   flat ushort index = ((g*KS + ks)*64 + lane)*8 + e
// Same packing serves MFMA A (index=row) and B (index=col); any bijective
// k-permutation cancels when both operands use it.

// ---------------------------------------------------------------------------
// Kernel 0: split W[128][2048] into packed bf16 hi/lo fragments. Zeroes out.
// ---------------------------------------------------------------------------
__global__ __launch_bounds__(256) void wsplit_kernel(
    const float* __restrict__ W,
    unsigned short* __restrict__ Whp, unsigned short* __restrict__ Wlp,
    float* __restrict__ out)
{
    int t = blockIdx.x * 256 + threadIdx.x;      // 32768 total
    if (t == 0) out[0] = 0.f;
    int l  = t & 63;
    int ks = (t >> 6) & 63;
    int g  = t >> 12;                            // 0..7
    int c  = g * 16 + (l & 15);
    int k0 = ks * 32 + ((l >> 4) << 3);
    const float* src = W + (size_t)c * DIN + k0;
    f32x4 v0 = *(const f32x4*)src;
    f32x4 v1 = *(const f32x4*)(src + 4);
    u32x4 hv, lv;
    PackedPair p0 = split2(v0[0], v0[1]);  hv[0] = p0.h; lv[0] = p0.l;
    PackedPair p1 = split2(v0[2], v0[3]);  hv[1] = p1.h; lv[1] = p1.l;
    PackedPair p2 = split2(v1[0], v1[1]);  hv[2] = p2.h; lv[2] = p2.l;
    PackedPair p3 = split2(v1[2], v1[3]);  hv[3] = p3.h; lv[3] = p3.l;
    size_t off = ((size_t)(g * 64 + ks) * 64 + l) * 8;
    *(u32x4*)(Whp + off) = hv;
    *(u32x4*)(Wlp + off) = lv;
}

// ---------------------------------------------------------------------------
// Kernel 1: h = relu(Z) @ W^T + b, rownorm, split+pack into Zhp/Zlp.
// 512 blocks x 512 thr (8 waves), 16 rows/block, split-K 8 => 4096 waves
// (4/SIMD). Per-iteration z prefetch double-buffer hides HBM latency.
// ---------------------------------------------------------------------------
__global__ __launch_bounds__(512, 4) void proj_kernel(
    const float* __restrict__ zi, const float* __restrict__ zj,
    const unsigned short* __restrict__ Whp, const unsigned short* __restrict__ Wlp,
    const float* __restrict__ bvec,
    unsigned short* __restrict__ Zhp, unsigned short* __restrict__ Zlp)
{
    __shared__ float Red[4][16][132];            // 33.8 KB, pad keeps dumps <=2-way
    const int t = threadIdx.x;
    const int w = t >> 6;                        // 0..7
    const int lane = t & 63;
    const int r15 = lane & 15, q = lane >> 4;
    const int row0 = blockIdx.x * 16;
    const float* zsrc = (row0 < BHALF) ? zi : zj;
    const int zr0 = (row0 < BHALF) ? row0 : row0 - BHALF;

    f32x4 acc[8];
    #pragma unroll
    for (int g = 0; g < 8; g++) acc[g] = (f32x4){0.f, 0.f, 0.f, 0.f};

    // lane's fixed z row; wave w owns K range [w*256, w*256+256)
    const float* zrow = zsrc + (size_t)(zr0 + r15) * DIN + q * 8;
    f32x4 pv0 = *(const f32x4*)(zrow + w * 256);
    f32x4 pv1 = *(const f32x4*)(zrow + w * 256 + 4);

    #pragma unroll
    for (int i = 0; i < 8; i++) {
        const int ks = w * 8 + i;
        f32x4 v0 = pv0, v1 = pv1;
        if (i < 7) {   // prefetch next iteration's z while this one computes
            pv0 = *(const f32x4*)(zrow + w * 256 + (i + 1) * 32);
            pv1 = *(const f32x4*)(zrow + w * 256 + (i + 1) * 32 + 4);
        }
        #pragma unroll
        for (int p = 0; p < 4; p++) {
            v0[p] = fmaxf(v0[p], 0.f);
            v1[p] = fmaxf(v1[p], 0.f);
        }
        u32x4 hv, lv;
        PackedPair p0 = split2(v0[0], v0[1]);  hv[0] = p0.h; lv[0] = p0.l;
        PackedPair p1 = split2(v0[2], v0[3]);  hv[1] = p1.h; lv[1] = p1.l;
        PackedPair p2 = split2(v1[0], v1[1]);  hv[2] = p2.h; lv[2] = p2.l;
        PackedPair p3 = split2(v1[2], v1[3]);  hv[3] = p3.h; lv[3] = p3.l;
        bf16x8 ah = __builtin_bit_cast(bf16x8, hv);
        bf16x8 al = __builtin_bit_cast(bf16x8, lv);
        #pragma unroll
        for (int g = 0; g < 8; g++) {
            size_t bo = ((size_t)(g * 64 + ks) * 64 + lane) * 8;
            bf16x8 bh = __builtin_bit_cast(bf16x8, *(const u32x4*)(Whp + bo));
            bf16x8 bl = __builtin_bit_cast(bf16x8, *(const u32x4*)(Wlp + bo));
            acc[g] = MFMA16(ah, bh, acc[g], 0, 0, 0);
            acc[g] = MFMA16(ah, bl, acc[g], 0, 0, 0);
            acc[g] = MFMA16(al, bh, acc[g], 0, 0, 0);
        }
    }

    // cross-wave reduce: waves 4-7 dump, 0-3 add
    if (w >= 4) {
        #pragma unroll
        for (int g = 0; g < 8; g++)
            #pragma unroll
            for (int r = 0; r < 4; r++)
                Red[w - 4][q * 4 + r][g * 16 + r15] = acc[g][r];
    }
    __syncthreads();
    if (w < 4) {
        #pragma unroll
        for (int g = 0; g < 8; g++)
            #pragma unroll
            for (int r = 0; r < 4; r++)
                Red[w][q * 4 + r][g * 16 + r15] += acc[g][r];
    }
    __syncthreads();

    // epilogue: 16 rows x 32 col-groups, one thread each
    const int row = t >> 5;       // 0..15
    const int tx  = t & 31;       // cols tx*4..+3
    float v[4];
    #pragma unroll
    for (int j = 0; j < 4; j++) {
        v[j] = Red[0][row][tx * 4 + j] + Red[1][row][tx * 4 + j]
             + Red[2][row][tx * 4 + j] + Red[3][row][tx * 4 + j];
    }
    const f32x4 bb = *(const f32x4*)(bvec + tx * 4);
    v[0] += bb[0]; v[1] += bb[1]; v[2] += bb[2]; v[3] += bb[3];
    float ssq = v[0]*v[0] + v[1]*v[1] + v[2]*v[2] + v[3]*v[3];
    #pragma unroll
    for (int msk = 1; msk < 32; msk <<= 1) ssq += __shfl_xor(ssq, msk);
    const float inv = 1.f / fmaxf(sqrtf(ssq), 1e-8f);
    const int grow = row0 + row;
    const int gg = grow >> 4, rr = grow & 15;
    #pragma unroll
    for (int j = 0; j < 4; j++) {
        const int k = tx * 4 + j;
        float x = v[j] * inv;
        unsigned int h  = bf16_rne(x);
        unsigned int lo = bf16_rne(x - bf16f(h));
        size_t off = (((size_t)gg * 4 + (k >> 5)) * 64
                      + (rr | (((k >> 3) & 3) << 4))) * 8 + (k & 7);
        Zhp[off] = (unsigned short)h;
        Zlp[off] = (unsigned short)lo;
    }
}

// ---------------------------------------------------------------------------
// Kernel 2: sim = (zn zn^T)/T fused exp/mask/pos + row partial sums.
// grid 1024 = 64 i-blocks (128 rows) x 16 j-splits (512 cols); 256 thr.
// 4 blocks/CU (4 waves/SIMD). Staging via global_load_lds width=16:
// LDS dest wave-uniform base + lane*16; identical layout to reg-staged R4.
// ---------------------------------------------------------------------------
__global__ __launch_bounds__(256, 4) void sim_kernel(
    const unsigned short* __restrict__ Zhp, const unsigned short* __restrict__ Zlp,
    float* __restrict__ Spart, float* __restrict__ P)
{
    __shared__ unsigned short Jt[16384];         // 32 KB, 32 chunks of 1KB
    const int t = threadIdx.x;
    const int w = t >> 6, lane = t & 63;
    const int r15 = lane & 15, rq = lane >> 4;
    const int iblk   = blockIdx.x >> 4;          // 0..63
    const int jsplit = blockIdx.x & 15;
    const int rowbase = iblk * 128 + w * 32;

    bf16x8 Ah[2][4], Al[2][4];
    #pragma unroll
    for (int m = 0; m < 2; m++) {
        const int gA = iblk * 8 + w * 2 + m;
        #pragma unroll
        for (int ks = 0; ks < 4; ks++) {
            size_t ao = (((size_t)gA * 4 + ks) * 64 + lane) * 8;
            Ah[m][ks] = __builtin_bit_cast(bf16x8, *(const u32x4*)(Zhp + ao));
            Al[m][ks] = __builtin_bit_cast(bf16x8, *(const u32x4*)(Zlp + ao));
        }
    }

    float rs[2][4], ps[2][4];
    #pragma unroll
    for (int m = 0; m < 2; m++)
        #pragma unroll
        for (int r = 0; r < 4; r++) { rs[m][r] = 0.f; ps[m][r] = 0.f; }

    for (int jt = 0; jt < JSPAN / 64; jt++) {    // 8 iterations
        const int j0 = jsplit * JSPAN + jt * 64;
        __syncthreads();                          // prev compute done; LDS free
        // async stage 64 cols x 128 k (hi+lo): 8 chunks per wave, 16B/lane
        #pragma unroll
        for (int rr = 0; rr < 8; rr++) {
            const int cid = rr * 4 + w;           // wave-uniform chunk id
            const int hl = cid >> 4, jg = (cid >> 2) & 3, ks = cid & 3;
            const unsigned short* src = hl ? Zlp : Zhp;
            const unsigned short* gp = src
                + (((size_t)((j0 >> 4) + jg) * 4 + ks) * 64 + lane) * 8;
            unsigned short* lp = &Jt[(size_t)(rr * 256 + w * 64) * 8];
            __builtin_amdgcn_global_load_lds(
                (const __attribute__((address_space(1))) unsigned int*)gp,
                (__attribute__((address_space(3))) unsigned int*)lp, 16, 0, 0);
        }
        __syncthreads();                          // drains vmcnt; LDS ready

        f32x4 acc[2][4];
        #pragma unroll
        for (int m = 0; m < 2; m++)
            #pragma unroll
            for (int jg = 0; jg < 4; jg++) acc[m][jg] = (f32x4){0.f,0.f,0.f,0.f};

        #pragma unroll
        for (int ks = 0; ks < 4; ks++) {
            #pragma unroll
            for (int jg = 0; jg < 4; jg++) {
                bf16x8 bh = __builtin_bit_cast(bf16x8,
                    *(const u32x4*)&Jt[((jg * 4 + ks) * 64 + lane) * 8]);
                bf16x8 bl = __builtin_bit_cast(bf16x8,
                    *(const u32x4*)&Jt[((jg * 4 + ks + 16) * 64 + lane) * 8]);
                #pragma unroll
                for (int m = 0; m < 2; m++) {
                    acc[m][jg] = MFMA16(Ah[m][ks], bh, acc[m][jg], 0, 0, 0);
                    acc[m][jg] = MFMA16(Ah[m][ks], bl, acc[m][jg], 0, 0, 0);
                    acc[m][jg] = MFMA16(Al[m][ks], bh, acc[m][jg], 0, 0, 0);
                }
            }
        }

        // fused epilogue: s=2*dot, self-mask, exp-accumulate, pos capture
        #pragma unroll
        for (int m = 0; m < 2; m++) {
            const int growb = rowbase + m * 16 + rq * 4;
            #pragma unroll
            for (int jg = 0; jg < 4; jg++) {
                const int gcol = j0 + jg * 16 + r15;
                #pragma unroll
                for (int r = 0; r < 4; r++) {
                    float s = 2.f * acc[m][jg][r];   // sim <= ~2: no max-sub
                    const int grow = growb + r;
                    float e = __expf(s);
                    if (gcol == grow) e = 0.f;
                    rs[m][r] += e;
                    if (gcol == (grow ^ BHALF)) ps[m][r] += s;
                }
            }
        }
    }

    #pragma unroll
    for (int m = 0; m < 2; m++)
        #pragma unroll
        for (int r = 0; r < 4; r++) {
            float a = rs[m][r], p = ps[m][r];
            #pragma unroll
            for (int msk = 1; msk < 16; msk <<= 1) {
                a += __shfl_xor(a, msk);
                p += __shfl_xor(p, msk);
            }
            if (r15 == 0) {
                const int grow = rowbase + m * 16 + rq * 4 + r;
                Spart[jsplit * NTOT + grow] = a;
                if (((grow ^ BHALF) >> 9) == jsplit) P[grow] = p;
            }
        }
}

// ---------------------------------------------------------------------------
// Kernel 3: loss = mean_i( log(sum_sp Spart[sp][i]) - P[i] )
// ---------------------------------------------------------------------------
__global__ __launch_bounds__(256) void loss_kernel(
    const float* __restrict__ Spart, const float* __restrict__ P,
    float* __restrict__ out)
{
    const int i = blockIdx.x * 256 + threadIdx.x;
    float ssum = 0.f;
    #pragma unroll
    for (int sp = 0; sp < NSPLIT; sp++) ssum += Spart[sp * NTOT + i];
    float v = logf(ssum) - P[i];
    #pragma unroll
    for (int msk = 1; msk < 64; msk <<= 1) v += __shfl_xor(v, msk);
    __shared__ float red[4];
    if ((threadIdx.x & 63) == 0) red[threadIdx.x >> 6] = v;
    __syncthreads();
    if (threadIdx.x == 0)
        atomicAdd(out, (red[0] + red[1] + red[2] + red[3]) * (1.f / (float)NTOT));
}

// ---------------------------------------------------------------------------
extern "C" void kernel_launch(void* const* d_in, const int* in_sizes, int n_in,
                              void* d_out, int out_size, void* d_ws, size_t ws_size,
                              hipStream_t stream) {
    const float* zi = (const float*)d_in[0];
    const float* zj = (const float*)d_in[1];
    const float* W  = (const float*)d_in[2];
    const float* bv = (const float*)d_in[3];
    float* out = (float*)d_out;

    char* ws = (char*)d_ws;
    unsigned short* Whp = (unsigned short*)(ws);                     // 512 KB
    unsigned short* Wlp = (unsigned short*)(ws + (512 << 10));       // 512 KB
    unsigned short* Zhp = (unsigned short*)(ws + (1024 << 10));      // 2 MB
    unsigned short* Zlp = (unsigned short*)(ws + (3072 << 10));      // 2 MB
    // Spart/P alias the W-packed region: W frags are dead once proj finishes.
    float* Spart = (float*)(ws);                                     // 512 KB
    float* P     = (float*)(ws + (512 << 10));                       // 32 KB

    wsplit_kernel<<<128, 256, 0, stream>>>(W, Whp, Wlp, out);
    proj_kernel<<<512, 512, 0, stream>>>(zi, zj, Whp, Wlp, bv, Zhp, Zlp);
    sim_kernel<<<1024, 256, 0, stream>>>(Zhp, Zlp, Spart, P);
    loss_kernel<<<NTOT / 256, 256, 0, stream>>>(Spart, P, out);
}

// Round 6
// 171.224 us; speedup vs baseline: 1.1596x; 1.1596x over previous
//
#include <hip/hip_runtime.h>
#include <math.h>

#define DIN    2048
#define DOUT   128
#define BHALF  4096
#define NTOT   8192
#define NSPLIT 8
#define JSPAN  1024   // NTOT / NSPLIT

typedef __bf16 bf16x8 __attribute__((ext_vector_type(8)));
typedef float  f32x4  __attribute__((ext_vector_type(4)));
typedef unsigned int u32x4 __attribute__((ext_vector_type(4)));

#define MFMA16 __builtin_amdgcn_mfma_f32_16x16x32_bf16

struct PackedPair { unsigned int h, l; };

__device__ __forceinline__ unsigned int bf16_rne(float f) {
    unsigned int u = __float_as_uint(f);
    return (u + 0x7fffu + ((u >> 16) & 1u)) >> 16;
}
__device__ __forceinline__ float bf16f(unsigned int h) {
    return __uint_as_float(h << 16);
}
__device__ __forceinline__ PackedPair split2(float a, float b) {
    unsigned int h0 = bf16_rne(a), h1 = bf16_rne(b);
    unsigned int g0 = bf16_rne(a - bf16f(h0)), g1 = bf16_rne(b - bf16f(h1));
    PackedPair r;
    r.h = h0 | (h1 << 16);
    r.l = g0 | (g1 << 16);
    return r;
}

// Packed fragment layout for a matrix row r, feature k (K-tiles of 32):
//   group g = r>>4, ks = k>>5, lane = (r&15) | (((k>>3)&3)<<4), elem e = k&7
//   flat ushort index = ((g*KS + ks)*64 + lane)*8 + e
// Same packing serves MFMA A (index=row) and B (index=col); any bijective
// k-permutation cancels when both operands use it.

// ---------------------------------------------------------------------------
// Kernel 0: split W[128][2048] into packed bf16 hi/lo fragments. Zeroes out.
// ---------------------------------------------------------------------------
__global__ __launch_bounds__(256) void wsplit_kernel(
    const float* __restrict__ W,
    unsigned short* __restrict__ Whp, unsigned short* __restrict__ Wlp,
    float* __restrict__ out)
{
    int t = blockIdx.x * 256 + threadIdx.x;      // 32768 total
    if (t == 0) out[0] = 0.f;
    int l  = t & 63;
    int ks = (t >> 6) & 63;
    int g  = t >> 12;                            // 0..7
    int c  = g * 16 + (l & 15);
    int k0 = ks * 32 + ((l >> 4) << 3);
    const float* src = W + (size_t)c * DIN + k0;
    f32x4 v0 = *(const f32x4*)src;
    f32x4 v1 = *(const f32x4*)(src + 4);
    u32x4 hv, lv;
    PackedPair p0 = split2(v0[0], v0[1]);  hv[0] = p0.h; lv[0] = p0.l;
    PackedPair p1 = split2(v0[2], v0[3]);  hv[1] = p1.h; lv[1] = p1.l;
    PackedPair p2 = split2(v1[0], v1[1]);  hv[2] = p2.h; lv[2] = p2.l;
    PackedPair p3 = split2(v1[2], v1[3]);  hv[3] = p3.h; lv[3] = p3.l;
    size_t off = ((size_t)(g * 64 + ks) * 64 + l) * 8;
    *(u32x4*)(Whp + off) = hv;
    *(u32x4*)(Wlp + off) = lv;
}

// ---------------------------------------------------------------------------
// Kernel 1: h = relu(Z) @ W^T + b, rownorm, split+pack into Zhp/Zlp.
// (unchanged from R5 — to be tuned once its counters are visible)
// ---------------------------------------------------------------------------
__global__ __launch_bounds__(512, 4) void proj_kernel(
    const float* __restrict__ zi, const float* __restrict__ zj,
    const unsigned short* __restrict__ Whp, const unsigned short* __restrict__ Wlp,
    const float* __restrict__ bvec,
    unsigned short* __restrict__ Zhp, unsigned short* __restrict__ Zlp)
{
    __shared__ float Red[4][16][132];
    const int t = threadIdx.x;
    const int w = t >> 6;
    const int lane = t & 63;
    const int r15 = lane & 15, q = lane >> 4;
    const int row0 = blockIdx.x * 16;
    const float* zsrc = (row0 < BHALF) ? zi : zj;
    const int zr0 = (row0 < BHALF) ? row0 : row0 - BHALF;

    f32x4 acc[8];
    #pragma unroll
    for (int g = 0; g < 8; g++) acc[g] = (f32x4){0.f, 0.f, 0.f, 0.f};

    const float* zrow = zsrc + (size_t)(zr0 + r15) * DIN + q * 8;
    f32x4 pv0 = *(const f32x4*)(zrow + w * 256);
    f32x4 pv1 = *(const f32x4*)(zrow + w * 256 + 4);

    #pragma unroll
    for (int i = 0; i < 8; i++) {
        const int ks = w * 8 + i;
        f32x4 v0 = pv0, v1 = pv1;
        if (i < 7) {
            pv0 = *(const f32x4*)(zrow + w * 256 + (i + 1) * 32);
            pv1 = *(const f32x4*)(zrow + w * 256 + (i + 1) * 32 + 4);
        }
        #pragma unroll
        for (int p = 0; p < 4; p++) {
            v0[p] = fmaxf(v0[p], 0.f);
            v1[p] = fmaxf(v1[p], 0.f);
        }
        u32x4 hv, lv;
        PackedPair p0 = split2(v0[0], v0[1]);  hv[0] = p0.h; lv[0] = p0.l;
        PackedPair p1 = split2(v0[2], v0[3]);  hv[1] = p1.h; lv[1] = p1.l;
        PackedPair p2 = split2(v1[0], v1[1]);  hv[2] = p2.h; lv[2] = p2.l;
        PackedPair p3 = split2(v1[2], v1[3]);  hv[3] = p3.h; lv[3] = p3.l;
        bf16x8 ah = __builtin_bit_cast(bf16x8, hv);
        bf16x8 al = __builtin_bit_cast(bf16x8, lv);
        #pragma unroll
        for (int g = 0; g < 8; g++) {
            size_t bo = ((size_t)(g * 64 + ks) * 64 + lane) * 8;
            bf16x8 bh = __builtin_bit_cast(bf16x8, *(const u32x4*)(Whp + bo));
            bf16x8 bl = __builtin_bit_cast(bf16x8, *(const u32x4*)(Wlp + bo));
            acc[g] = MFMA16(ah, bh, acc[g], 0, 0, 0);
            acc[g] = MFMA16(ah, bl, acc[g], 0, 0, 0);
            acc[g] = MFMA16(al, bh, acc[g], 0, 0, 0);
        }
    }

    if (w >= 4) {
        #pragma unroll
        for (int g = 0; g < 8; g++)
            #pragma unroll
            for (int r = 0; r < 4; r++)
                Red[w - 4][q * 4 + r][g * 16 + r15] = acc[g][r];
    }
    __syncthreads();
    if (w < 4) {
        #pragma unroll
        for (int g = 0; g < 8; g++)
            #pragma unroll
            for (int r = 0; r < 4; r++)
                Red[w][q * 4 + r][g * 16 + r15] += acc[g][r];
    }
    __syncthreads();

    const int row = t >> 5;
    const int tx  = t & 31;
    float v[4];
    #pragma unroll
    for (int j = 0; j < 4; j++) {
        v[j] = Red[0][row][tx * 4 + j] + Red[1][row][tx * 4 + j]
             + Red[2][row][tx * 4 + j] + Red[3][row][tx * 4 + j];
    }
    const f32x4 bb = *(const f32x4*)(bvec + tx * 4);
    v[0] += bb[0]; v[1] += bb[1]; v[2] += bb[2]; v[3] += bb[3];
    float ssq = v[0]*v[0] + v[1]*v[1] + v[2]*v[2] + v[3]*v[3];
    #pragma unroll
    for (int msk = 1; msk < 32; msk <<= 1) ssq += __shfl_xor(ssq, msk);
    const float inv = 1.f / fmaxf(sqrtf(ssq), 1e-8f);
    const int grow = row0 + row;
    const int gg = grow >> 4, rr = grow & 15;
    #pragma unroll
    for (int j = 0; j < 4; j++) {
        const int k = tx * 4 + j;
        float x = v[j] * inv;
        unsigned int h  = bf16_rne(x);
        unsigned int lo = bf16_rne(x - bf16f(h));
        size_t off = (((size_t)gg * 4 + (k >> 5)) * 64
                      + (rr | (((k >> 3) & 3) << 4))) * 8 + (k & 7);
        Zhp[off] = (unsigned short)h;
        Zlp[off] = (unsigned short)lo;
    }
}

// ---------------------------------------------------------------------------
// Kernel 2: sim = (zn zn^T)/T fused exp/mask/pos + row partial sums.
// grid 512 = 64 i-blocks (128 rows) x 8 j-splits (jsplit = blk&7 == XCD id,
// so all blocks on one XCD share B-tiles -> per-XCD L2 hit). 256 thr, 2
// blocks/CU (64 KB LDS dbuf). Pipeline: issue stage(t+1) -> vmcnt(8) waits
// only stage(t) -> raw s_barrier (NO vmcnt(0) drain) -> compute -> barrier.
// ---------------------------------------------------------------------------
__global__ __launch_bounds__(256, 2) void sim_kernel(
    const unsigned short* __restrict__ Zhp, const unsigned short* __restrict__ Zlp,
    float* __restrict__ Spart, float* __restrict__ P)
{
    __shared__ unsigned short Jt[2][16384];      // 2 x 32 KB double buffer
    const int t = threadIdx.x;
    const int w = t >> 6, lane = t & 63;
    const int r15 = lane & 15, rq = lane >> 4;
    const int jsplit = blockIdx.x & 7;           // same-XCD blocks share j-range
    const int iblk   = blockIdx.x >> 3;          // 0..63
    const int rowbase = iblk * 128 + w * 32;
    const int j0base  = jsplit * JSPAN;

    // stage 64 cols x 128 k (hi+lo) = 32 chunks of 1KB; 8 chunks per wave,
    // LDS dest = wave-uniform base + lane*16 (global_load_lds contract).
#define STAGE(jt_, buf_) do {                                                 \
        const int jref_ = (j0base >> 4) + (jt_) * 4;                          \
        _Pragma("unroll")                                                     \
        for (int rr_ = 0; rr_ < 8; rr_++) {                                   \
            const int cid_ = rr_ * 4 + w;                                     \
            const int hl_ = cid_ >> 4, jg_ = (cid_ >> 2) & 3, ks_ = cid_ & 3; \
            const unsigned short* src_ = hl_ ? Zlp : Zhp;                     \
            const unsigned short* gp_ = src_ +                                \
                (((size_t)(jref_ + jg_) * 4 + ks_) * 64 + lane) * 8;          \
            unsigned short* lp_ = &Jt[buf_][(cid_ * 64) * 8];                 \
            __builtin_amdgcn_global_load_lds(                                 \
                (const __attribute__((address_space(1))) unsigned int*)gp_,   \
                (__attribute__((address_space(3))) unsigned int*)lp_,         \
                16, 0, 0);                                                    \
        } } while (0)

    STAGE(0, 0);   // prologue: tile 0 into buffer 0

    // A fragments: 32 rows x 128 k, hi+lo, register-resident all kernel
    bf16x8 Ah[2][4], Al[2][4];
    #pragma unroll
    for (int m = 0; m < 2; m++) {
        const int gA = iblk * 8 + w * 2 + m;
        #pragma unroll
        for (int ks = 0; ks < 4; ks++) {
            size_t ao = (((size_t)gA * 4 + ks) * 64 + lane) * 8;
            Ah[m][ks] = __builtin_bit_cast(bf16x8, *(const u32x4*)(Zhp + ao));
            Al[m][ks] = __builtin_bit_cast(bf16x8, *(const u32x4*)(Zlp + ao));
        }
    }

    float rs[2][4], ps[2][4];
    #pragma unroll
    for (int m = 0; m < 2; m++)
        #pragma unroll
        for (int r = 0; r < 4; r++) { rs[m][r] = 0.f; ps[m][r] = 0.f; }

    #pragma unroll 2
    for (int jt = 0; jt < 16; jt++) {
        const int cur = jt & 1;
        const int j0 = j0base + jt * 64;
        if (jt < 15) {
            STAGE(jt + 1, cur ^ 1);
            asm volatile("s_waitcnt vmcnt(8)" ::: "memory");  // tile jt landed
        } else {
            asm volatile("s_waitcnt vmcnt(0)" ::: "memory");
        }
        __builtin_amdgcn_s_barrier();            // raw: no vmcnt(0) drain
        __builtin_amdgcn_sched_barrier(0);

        const unsigned short* J = &Jt[cur][0];
        f32x4 acc[2][4];
        #pragma unroll
        for (int m = 0; m < 2; m++)
            #pragma unroll
            for (int jg = 0; jg < 4; jg++) acc[m][jg] = (f32x4){0.f,0.f,0.f,0.f};

        #pragma unroll
        for (int ks = 0; ks < 4; ks++) {
            #pragma unroll
            for (int jg = 0; jg < 4; jg++) {
                bf16x8 bh = __builtin_bit_cast(bf16x8,
                    *(const u32x4*)&J[((jg * 4 + ks) * 64 + lane) * 8]);
                bf16x8 bl = __builtin_bit_cast(bf16x8,
                    *(const u32x4*)&J[((jg * 4 + ks + 16) * 64 + lane) * 8]);
                #pragma unroll
                for (int m = 0; m < 2; m++) {
                    acc[m][jg] = MFMA16(Ah[m][ks], bh, acc[m][jg], 0, 0, 0);
                    acc[m][jg] = MFMA16(Ah[m][ks], bl, acc[m][jg], 0, 0, 0);
                    acc[m][jg] = MFMA16(Al[m][ks], bh, acc[m][jg], 0, 0, 0);
                }
            }
        }

        // epilogue: diag/pos are 16-aligned ranges -> wave-uniform tile test
        #pragma unroll
        for (int m = 0; m < 2; m++) {
            const int rb16 = rowbase + m * 16;
            #pragma unroll
            for (int jg = 0; jg < 4; jg++) {
                const int cb16 = j0 + jg * 16;
                if (cb16 != rb16 && cb16 != (rb16 ^ BHALF)) {
                    #pragma unroll
                    for (int r = 0; r < 4; r++)
                        rs[m][r] += __expf(2.f * acc[m][jg][r]);
                } else {
                    const int gcol = cb16 + r15;
                    #pragma unroll
                    for (int r = 0; r < 4; r++) {
                        float s = 2.f * acc[m][jg][r];
                        const int grow = rb16 + rq * 4 + r;
                        float e = __expf(s);
                        if (gcol == grow) e = 0.f;
                        rs[m][r] += e;
                        if (gcol == (grow ^ BHALF)) ps[m][r] += s;
                    }
                }
            }
        }
        __builtin_amdgcn_sched_barrier(0);
        __builtin_amdgcn_s_barrier();            // buffer free for next stage
    }
#undef STAGE

    #pragma unroll
    for (int m = 0; m < 2; m++)
        #pragma unroll
        for (int r = 0; r < 4; r++) {
            float a = rs[m][r], p = ps[m][r];
            #pragma unroll
            for (int msk = 1; msk < 16; msk <<= 1) {
                a += __shfl_xor(a, msk);
                p += __shfl_xor(p, msk);
            }
            if (r15 == 0) {
                const int grow = rowbase + m * 16 + rq * 4 + r;
                Spart[jsplit * NTOT + grow] = a;
                if (((grow ^ BHALF) >> 10) == jsplit) P[grow] = p;
            }
        }
}

// ---------------------------------------------------------------------------
// Kernel 3: loss = mean_i( log(sum_sp Spart[sp][i]) - P[i] )
// ---------------------------------------------------------------------------
__global__ __launch_bounds__(256) void loss_kernel(
    const float* __restrict__ Spart, const float* __restrict__ P,
    float* __restrict__ out)
{
    const int i = blockIdx.x * 256 + threadIdx.x;
    float ssum = 0.f;
    #pragma unroll
    for (int sp = 0; sp < NSPLIT; sp++) ssum += Spart[sp * NTOT + i];
    float v = logf(ssum) - P[i];
    #pragma unroll
    for (int msk = 1; msk < 64; msk <<= 1) v += __shfl_xor(v, msk);
    __shared__ float red[4];
    if ((threadIdx.x & 63) == 0) red[threadIdx.x >> 6] = v;
    __syncthreads();
    if (threadIdx.x == 0)
        atomicAdd(out, (red[0] + red[1] + red[2] + red[3]) * (1.f / (float)NTOT));
}

// ---------------------------------------------------------------------------
extern "C" void kernel_launch(void* const* d_in, const int* in_sizes, int n_in,
                              void* d_out, int out_size, void* d_ws, size_t ws_size,
                              hipStream_t stream) {
    const float* zi = (const float*)d_in[0];
    const float* zj = (const float*)d_in[1];
    const float* W  = (const float*)d_in[2];
    const float* bv = (const float*)d_in[3];
    float* out = (float*)d_out;

    char* ws = (char*)d_ws;
    unsigned short* Whp = (unsigned short*)(ws);                     // 512 KB
    unsigned short* Wlp = (unsigned short*)(ws + (512 << 10));       // 512 KB
    unsigned short* Zhp = (unsigned short*)(ws + (1024 << 10));      // 2 MB
    unsigned short* Zlp = (unsigned short*)(ws + (3072 << 10));      // 2 MB
    // Spart/P alias the W-packed region: W frags are dead once proj finishes.
    float* Spart = (float*)(ws);                                     // 256 KB
    float* P     = (float*)(ws + (256 << 10));                       // 32 KB

    wsplit_kernel<<<128, 256, 0, stream>>>(W, Whp, Wlp, out);
    proj_kernel<<<512, 512, 0, stream>>>(zi, zj, Whp, Wlp, bv, Zhp, Zlp);
    sim_kernel<<<512, 256, 0, stream>>>(Zhp, Zlp, Spart, P);
    loss_kernel<<<NTOT / 256, 256, 0, stream>>>(Spart, P, out);
}